// Round 1
// baseline (1176.745 us; speedup 1.0000x reference)
//
#include <hip/hip_runtime.h>
#include <math.h>

// Problem constants (fixed by setup_inputs):
//   B=4, Nc=Nt=2048, D=512, H=8, E=64, scale = 1/head_dim = 1/64 (NOT 1/sqrt)
#define B_   4
#define NSEQ 2048
#define D_   512
#define H_   8
#define E_   64

// ---------------------------------------------------------------------------
// Projection: Y[b,h,n,e] = sum_d X[b,n,d] * W[h,d,e]
// Per (b,h): [2048,512] x [512,64] GEMM. 64x64 output tile per block,
// K-tile 32, 256 threads, 4x4 accum per thread.
// ---------------------------------------------------------------------------
__global__ __launch_bounds__(256)
void proj_kernel(const float* __restrict__ X, const float* __restrict__ W,
                 float* __restrict__ Y) {
    const int ntile = blockIdx.x;   // 32 tiles of 64 rows
    const int h     = blockIdx.y;
    const int b     = blockIdx.z;
    const int tid = threadIdx.x;
    const int tx = tid & 15, ty = tid >> 4;

    __shared__ float As[64][33];   // +1 pad
    __shared__ float Bs[32][65];

    float acc[4][4] = {};
    const int n0 = ntile * 64;
    const float* Xp = X + ((size_t)b * NSEQ + n0) * D_;
    const float* Wp = W + (size_t)h * D_ * E_;

    for (int kt = 0; kt < D_; kt += 32) {
        #pragma unroll
        for (int i = 0; i < 8; ++i) {           // A tile 64x32
            int idx = tid + i * 256;
            int r = idx >> 5, c = idx & 31;
            As[r][c] = Xp[(size_t)r * D_ + kt + c];
        }
        #pragma unroll
        for (int i = 0; i < 8; ++i) {           // B tile 32x64
            int idx = tid + i * 256;
            int r = idx >> 6, c = idx & 63;
            Bs[r][c] = Wp[(size_t)(kt + r) * E_ + c];
        }
        __syncthreads();
        #pragma unroll
        for (int kk = 0; kk < 32; ++kk) {
            float a[4], bb[4];
            #pragma unroll
            for (int i = 0; i < 4; ++i) a[i] = As[ty * 4 + i][kk];
            #pragma unroll
            for (int j = 0; j < 4; ++j) bb[j] = Bs[kk][tx * 4 + j];
            #pragma unroll
            for (int i = 0; i < 4; ++i)
                #pragma unroll
                for (int j = 0; j < 4; ++j) acc[i][j] += a[i] * bb[j];
        }
        __syncthreads();
    }

    float* Yp = Y + (((size_t)b * H_ + h) * NSEQ + n0) * E_;
    #pragma unroll
    for (int i = 0; i < 4; ++i)
        #pragma unroll
        for (int j = 0; j < 4; ++j)
            Yp[(size_t)(ty * 4 + i) * E_ + tx * 4 + j] = acc[i][j];
}

// ---------------------------------------------------------------------------
// Flash attention (fp32). One block per (b, h, 64-row Q tile).
// Online softmax; K and V share one LDS buffer (V loaded after S is done).
// Writes head-concat layout O[b, n, h*64+e] so output proj is a plain GEMM.
// ---------------------------------------------------------------------------
__global__ __launch_bounds__(256)
void attn_kernel(const float* __restrict__ Q, const float* __restrict__ K,
                 const float* __restrict__ V, float* __restrict__ O) {
    const int qt = blockIdx.x;   // 32 Q tiles
    const int h  = blockIdx.y;
    const int b  = blockIdx.z;
    const int tid = threadIdx.x;
    const int tx = tid & 15, ty = tid >> 4;

    __shared__ float Qs[64][65];
    __shared__ float KVs[64][65];   // K tile, then reused for V tile
    __shared__ float Ps[64][65];    // scores, then exp'd P
    __shared__ float mrow[64], lrow[64], arow[64];

    const size_t base = ((size_t)b * H_ + h) * NSEQ;
    const int n0 = qt * 64;

    #pragma unroll
    for (int i = 0; i < 16; ++i) {              // load Q tile 64x64
        int idx = tid + i * 256;
        int r = idx >> 6, c = idx & 63;
        Qs[r][c] = Q[(base + n0 + r) * E_ + c];
    }
    if (tid < 64) { mrow[tid] = -1e30f; lrow[tid] = 0.f; }

    float oacc[4][4] = {};
    const float scale = 1.0f / 64.0f;   // divide by head_dim, per reference

    for (int j = 0; j < NSEQ / 64; ++j) {
        // ---- load K tile
        #pragma unroll
        for (int i = 0; i < 16; ++i) {
            int idx = tid + i * 256;
            int r = idx >> 6, c = idx & 63;
            KVs[r][c] = K[(base + j * 64 + r) * E_ + c];
        }
        __syncthreads();   // barrier A: Q/K (and prev-iter P/V reads) settled

        // ---- S = (Q K^T) * scale, 4x4 per thread
        float sacc[4][4] = {};
        #pragma unroll
        for (int e = 0; e < 64; ++e) {
            float a[4], bb[4];
            #pragma unroll
            for (int i = 0; i < 4; ++i) a[i] = Qs[ty * 4 + i][e];
            #pragma unroll
            for (int jj = 0; jj < 4; ++jj) bb[jj] = KVs[tx * 4 + jj][e];
            #pragma unroll
            for (int i = 0; i < 4; ++i)
                #pragma unroll
                for (int jj = 0; jj < 4; ++jj) sacc[i][jj] += a[i] * bb[jj];
        }
        #pragma unroll
        for (int i = 0; i < 4; ++i)
            #pragma unroll
            for (int jj = 0; jj < 4; ++jj)
                Ps[ty * 4 + i][tx * 4 + jj] = sacc[i][jj] * scale;
        __syncthreads();   // barrier B: S visible; K reads done

        // ---- online softmax: 4 lanes per row (consecutive lanes, same wave)
        {
            const int row = tid >> 2, part = tid & 3;
            float pv[16];
            float tmax = -1e30f;
            #pragma unroll
            for (int c = 0; c < 16; ++c) {
                float s = Ps[row][part * 16 + c];
                pv[c] = s;
                tmax = fmaxf(tmax, s);
            }
            tmax = fmaxf(tmax, __shfl_xor(tmax, 1));
            tmax = fmaxf(tmax, __shfl_xor(tmax, 2));
            const float mold = mrow[row];
            const float mnew = fmaxf(mold, tmax);
            const float al   = __expf(mold - mnew);
            float lsum = 0.f;
            #pragma unroll
            for (int c = 0; c < 16; ++c) {
                float p = __expf(pv[c] - mnew);
                Ps[row][part * 16 + c] = p;
                lsum += p;
            }
            lsum += __shfl_xor(lsum, 1);
            lsum += __shfl_xor(lsum, 2);
            if (part == 0) {
                mrow[row] = mnew;
                lrow[row] = lrow[row] * al + lsum;
                arow[row] = al;
            }
        }
        // ---- load V tile into the (now free) K buffer
        #pragma unroll
        for (int i = 0; i < 16; ++i) {
            int idx = tid + i * 256;
            int r = idx >> 6, c = idx & 63;
            KVs[r][c] = V[(base + j * 64 + r) * E_ + c];
        }
        __syncthreads();   // barrier C: P, V, m/l/alpha visible

        // ---- rescale O and accumulate P·V
        #pragma unroll
        for (int i = 0; i < 4; ++i) {
            const float al = arow[ty * 4 + i];
            #pragma unroll
            for (int jj = 0; jj < 4; ++jj) oacc[i][jj] *= al;
        }
        #pragma unroll
        for (int p = 0; p < 64; ++p) {
            float a[4], bb[4];
            #pragma unroll
            for (int i = 0; i < 4; ++i) a[i] = Ps[ty * 4 + i][p];
            #pragma unroll
            for (int jj = 0; jj < 4; ++jj) bb[jj] = KVs[p][tx * 4 + jj];
            #pragma unroll
            for (int i = 0; i < 4; ++i)
                #pragma unroll
                for (int jj = 0; jj < 4; ++jj) oacc[i][jj] += a[i] * bb[jj];
        }
        __syncthreads();   // barrier D: P/V reads done before next-iter stores
    }

    // ---- epilogue: divide by l, store head-concat layout
    #pragma unroll
    for (int i = 0; i < 4; ++i) {
        const float inv = 1.0f / lrow[ty * 4 + i];
        #pragma unroll
        for (int jj = 0; jj < 4; ++jj)
            O[((size_t)b * NSEQ + n0 + ty * 4 + i) * D_ + h * E_ + tx * 4 + jj] =
                oacc[i][jj] * inv;
    }
}

// ---------------------------------------------------------------------------
// Output projection: Out[m,o] = sum_d A[m,d] * Wout[o,d]   (x @ Wout^T)
// M = B*NSEQ = 8192, K = N = 512. NT-GEMM, 64x64 tiles.
// ---------------------------------------------------------------------------
__global__ __launch_bounds__(256)
void outproj_kernel(const float* __restrict__ A, const float* __restrict__ Wout,
                    float* __restrict__ Out) {
    const int mt = blockIdx.x;   // 128
    const int ot = blockIdx.y;   // 8
    const int tid = threadIdx.x;
    const int tx = tid & 15, ty = tid >> 4;

    __shared__ float As[64][33];
    __shared__ float Bs[64][33];

    float acc[4][4] = {};
    const int m0 = mt * 64, o0 = ot * 64;

    for (int kt = 0; kt < D_; kt += 32) {
        #pragma unroll
        for (int i = 0; i < 8; ++i) {
            int idx = tid + i * 256;
            int r = idx >> 5, c = idx & 31;
            As[r][c] = A[(size_t)(m0 + r) * D_ + kt + c];
            Bs[r][c] = Wout[(size_t)(o0 + r) * D_ + kt + c];
        }
        __syncthreads();
        #pragma unroll
        for (int kk = 0; kk < 32; ++kk) {
            float a[4], bb[4];
            #pragma unroll
            for (int i = 0; i < 4; ++i) a[i] = As[ty * 4 + i][kk];
            #pragma unroll
            for (int j = 0; j < 4; ++j) bb[j] = Bs[tx * 4 + j][kk];
            #pragma unroll
            for (int i = 0; i < 4; ++i)
                #pragma unroll
                for (int j = 0; j < 4; ++j) acc[i][j] += a[i] * bb[j];
        }
        __syncthreads();
    }
    #pragma unroll
    for (int i = 0; i < 4; ++i)
        #pragma unroll
        for (int j = 0; j < 4; ++j)
            Out[(size_t)(m0 + ty * 4 + i) * D_ + o0 + tx * 4 + j] = acc[i][j];
}

// ---------------------------------------------------------------------------
extern "C" void kernel_launch(void* const* d_in, const int* in_sizes, int n_in,
                              void* d_out, int out_size, void* d_ws, size_t ws_size,
                              hipStream_t stream) {
    const float* keys   = (const float*)d_in[0];
    const float* values = (const float*)d_in[1];
    const float* query  = (const float*)d_in[2];
    const float* Wk     = (const float*)d_in[3];
    const float* Wv     = (const float*)d_in[4];
    const float* Wq     = (const float*)d_in[5];
    const float* Wout   = (const float*)d_in[6];
    float* out = (float*)d_out;
    float* ws  = (float*)d_ws;

    const size_t BHNE = (size_t)B_ * H_ * NSEQ * E_;   // 4,194,304
    float* q  = ws;
    float* k  = ws + BHNE;
    float* v  = ws + 2 * BHNE;
    float* ao = ws + 3 * BHNE;    // head-concat attention output [B, NSEQ, D]

    dim3 pgrid(NSEQ / 64, H_, B_);   // 1024 blocks
    proj_kernel<<<pgrid, 256, 0, stream>>>(query,  Wq, q);
    proj_kernel<<<pgrid, 256, 0, stream>>>(keys,   Wk, k);
    proj_kernel<<<pgrid, 256, 0, stream>>>(values, Wv, v);

    attn_kernel<<<dim3(NSEQ / 64, H_, B_), 256, 0, stream>>>(q, k, v, ao);

    outproj_kernel<<<dim3((B_ * NSEQ) / 64, D_ / 64), 256, 0, stream>>>(ao, Wout, out);
}

// Round 2
// 309.208 us; speedup vs baseline: 3.8057x; 3.8057x over previous
//
#include <hip/hip_runtime.h>

// B=4, H=8, Nt=Nc=2048, D=512, E=64, scale = 1/head_dim = 1/64
#define B_   4
#define H_   8
#define NSEQ 2048
#define D_   512
#define E_   64

typedef __bf16 bf16x8 __attribute__((ext_vector_type(8)));
typedef float  f32x4  __attribute__((ext_vector_type(4)));

__device__ __forceinline__ unsigned short f2b(float f) {
    __bf16 h = (__bf16)f;                      // RNE fptrunc
    return __builtin_bit_cast(unsigned short, h);
}
__device__ __forceinline__ bf16x8 frag(const unsigned short* p) {
    return *reinterpret_cast<const bf16x8*>(p);
}

// ---------------------------------------------------------------------------
// Cast X tensors (keys/values/query) fp32 -> bf16, same layout [B][N][D].
// ---------------------------------------------------------------------------
__global__ __launch_bounds__(256)
void cast_x_kernel(const float* __restrict__ xk, const float* __restrict__ xv,
                   const float* __restrict__ xq,
                   unsigned short* __restrict__ ok, unsigned short* __restrict__ ov,
                   unsigned short* __restrict__ oq) {
    const float* src = blockIdx.y == 0 ? xk : (blockIdx.y == 1 ? xv : xq);
    unsigned short* dst = blockIdx.y == 0 ? ok : (blockIdx.y == 1 ? ov : oq);
    size_t i = ((size_t)blockIdx.x * 256 + threadIdx.x) * 4;
    float4 f = *reinterpret_cast<const float4*>(src + i);
    ushort4 o = make_ushort4(f2b(f.x), f2b(f.y), f2b(f.z), f2b(f.w));
    *reinterpret_cast<ushort4*>(dst + i) = o;
}

// ---------------------------------------------------------------------------
// Cast + transpose W tensors: [H][D][E] fp32 -> [H][E][D] bf16 (y=0..2),
// Wout [O][D] fp32 -> same layout bf16 (y=3).
// ---------------------------------------------------------------------------
__global__ __launch_bounds__(256)
void cast_w_kernel(const float* __restrict__ Wk, const float* __restrict__ Wv,
                   const float* __restrict__ Wq, const float* __restrict__ Wo,
                   unsigned short* __restrict__ okt, unsigned short* __restrict__ ovt,
                   unsigned short* __restrict__ oqt, unsigned short* __restrict__ oo) {
    int idx = blockIdx.x * 256 + threadIdx.x;   // < 262144
    int y = blockIdx.y;
    if (y == 3) { oo[idx] = f2b(Wo[idx]); return; }
    const float* src = y == 0 ? Wk : (y == 1 ? Wv : Wq);
    unsigned short* dst = y == 0 ? okt : (y == 1 ? ovt : oqt);
    int hh = idx >> 15, rem = idx & 32767, d = rem >> 6, e = rem & 63;
    dst[hh * 32768 + e * 512 + d] = f2b(src[idx]);
}

// ---------------------------------------------------------------------------
// Projection GEMM: C[m][e] = sum_d X[m][d] * Wt[e][d].  Per (b,h): 2048x64x512.
// Block: 128(m) x 64(e), 4 waves, each wave 32 rows; K-chunk 32 (1 MFMA depth).
// VMODE 0: write natural [n][e] bf16 (Q,K). VMODE 1: write transposed [e][n] (V).
// ---------------------------------------------------------------------------
template<int VMODE>
__global__ __launch_bounds__(256)
void proj_kernel(const unsigned short* __restrict__ X,
                 const unsigned short* __restrict__ Wt,
                 unsigned short* __restrict__ Y) {
    const int n0 = blockIdx.x * 128;
    const int h = blockIdx.y, b = blockIdx.z;
    const int tid = threadIdx.x;
    const int wave = tid >> 6, lane = tid & 63;
    const int quad = lane >> 4, l16 = lane & 15;

    __shared__ unsigned short smem[128 * 72];   // 18.4 KB; staging uses 7680 of it
    unsigned short (*As)[40] = reinterpret_cast<unsigned short(*)[40]>(smem);
    unsigned short (*Bs)[40] = reinterpret_cast<unsigned short(*)[40]>(smem + 128 * 40);
    unsigned short (*Os)[72] = reinterpret_cast<unsigned short(*)[72]>(smem);

    const unsigned short* Xp = X + ((size_t)b * NSEQ + n0) * D_;
    const unsigned short* Wp = Wt + (size_t)h * E_ * D_;

    const f32x4 z = {0.f, 0.f, 0.f, 0.f};
    f32x4 acc[2][4];
    #pragma unroll
    for (int i = 0; i < 2; ++i)
        #pragma unroll
        for (int j = 0; j < 4; ++j) acc[i][j] = z;

    for (int kt = 0; kt < D_; kt += 32) {
        #pragma unroll
        for (int i = 0; i < 2; ++i) {           // A tile 128x32
            int c = tid + i * 256;
            int r = c >> 2, col = (c & 3) * 8;
            *reinterpret_cast<uint4*>(&As[r][col]) =
                *reinterpret_cast<const uint4*>(Xp + (size_t)r * D_ + kt + col);
        }
        {                                        // B tile 64x32 (rows = e)
            int r = tid >> 2, col = (tid & 3) * 8;
            *reinterpret_cast<uint4*>(&Bs[r][col]) =
                *reinterpret_cast<const uint4*>(Wp + (size_t)r * D_ + kt + col);
        }
        __syncthreads();
        bf16x8 bf[4];
        #pragma unroll
        for (int nt = 0; nt < 4; ++nt) bf[nt] = frag(&Bs[nt * 16 + l16][quad * 8]);
        #pragma unroll
        for (int mt2 = 0; mt2 < 2; ++mt2) {
            bf16x8 af = frag(&As[wave * 32 + mt2 * 16 + l16][quad * 8]);
            #pragma unroll
            for (int nt = 0; nt < 4; ++nt)
                acc[mt2][nt] = __builtin_amdgcn_mfma_f32_16x16x32_bf16(
                    af, bf[nt], acc[mt2][nt], 0, 0, 0);
        }
        __syncthreads();
    }

    if (VMODE == 0) {
        // LDS round-trip for coalesced bf16 stores; tile is contiguous 16 KB.
        #pragma unroll
        for (int mt2 = 0; mt2 < 2; ++mt2)
            #pragma unroll
            for (int nt = 0; nt < 4; ++nt)
                #pragma unroll
                for (int r = 0; r < 4; ++r)
                    Os[wave * 32 + mt2 * 16 + quad * 4 + r][nt * 16 + l16] =
                        f2b(acc[mt2][nt][r]);
        __syncthreads();
        unsigned short* Yp = Y + (((size_t)b * H_ + h) * NSEQ + n0) * E_;
        #pragma unroll
        for (int i = 0; i < 4; ++i) {
            int c = tid + i * 256;
            int r = c >> 3, col = (c & 7) * 8;
            *reinterpret_cast<uint4*>(Yp + (size_t)r * E_ + col) =
                *reinterpret_cast<const uint4*>(&Os[r][col]);
        }
    } else {
        // transposed output Vt[e][n]; 4 consecutive n live in regs r=0..3
        unsigned short* Yp = Y + ((size_t)b * H_ + h) * E_ * NSEQ;
        #pragma unroll
        for (int mt2 = 0; mt2 < 2; ++mt2)
            #pragma unroll
            for (int nt = 0; nt < 4; ++nt) {
                int e = nt * 16 + l16;
                int n = n0 + wave * 32 + mt2 * 16 + quad * 4;
                ushort4 pv = make_ushort4(f2b(acc[mt2][nt][0]), f2b(acc[mt2][nt][1]),
                                          f2b(acc[mt2][nt][2]), f2b(acc[mt2][nt][3]));
                *reinterpret_cast<ushort4*>(Yp + (size_t)e * NSEQ + n) = pv;
            }
    }
}

// ---------------------------------------------------------------------------
// Flash attention, bf16 MFMA. Block = 128 Q-rows per (b,h); 4 waves x 32 rows.
// Q [n][e] bf16, K [n][e] bf16, Vt [e][n] bf16. Output head-concat bf16.
// ---------------------------------------------------------------------------
__global__ __launch_bounds__(256)
void attn_kernel(const unsigned short* __restrict__ Qb,
                 const unsigned short* __restrict__ Kb,
                 const unsigned short* __restrict__ Vtb,
                 unsigned short* __restrict__ AOb) {
    const int n0 = blockIdx.x * 128;
    const int h = blockIdx.y, b = blockIdx.z;
    const int tid = threadIdx.x;
    const int wave = tid >> 6, lane = tid & 63;
    const int quad = lane >> 4, l16 = lane & 15;

    __shared__ unsigned short Qs[128][72];
    __shared__ unsigned short KVs[64][72];   // K tile, then V tile
    __shared__ unsigned short Ps[128][72];   // P (bf16), then O staging

    const size_t bh = (size_t)b * H_ + h;
    const unsigned short* qp = Qb + (bh * NSEQ + n0) * E_;
    const unsigned short* kp = Kb + bh * NSEQ * E_;
    const unsigned short* vp = Vtb + bh * E_ * NSEQ;

    #pragma unroll
    for (int i = 0; i < 4; ++i) {            // stage Q 128x64
        int c = tid + i * 256;
        int r = c >> 3, col = (c & 7) * 8;
        *reinterpret_cast<uint4*>(&Qs[r][col]) =
            *reinterpret_cast<const uint4*>(qp + (size_t)r * E_ + col);
    }

    const f32x4 z = {0.f, 0.f, 0.f, 0.f};
    f32x4 oacc[2][4];
    float mstate[2][4], lstate[2][4];
    #pragma unroll
    for (int i = 0; i < 2; ++i)
        #pragma unroll
        for (int j = 0; j < 4; ++j) { oacc[i][j] = z; }
    #pragma unroll
    for (int i = 0; i < 2; ++i)
        #pragma unroll
        for (int r = 0; r < 4; ++r) { mstate[i][r] = -1e30f; lstate[i][r] = 0.f; }

    const float inv64 = 0.015625f;

    for (int j = 0; j < NSEQ / 64; ++j) {
        #pragma unroll
        for (int i = 0; i < 2; ++i) {        // stage K tile 64x64
            int c = tid + i * 256;
            int r = c >> 3, col = (c & 7) * 8;
            *reinterpret_cast<uint4*>(&KVs[r][col]) =
                *reinterpret_cast<const uint4*>(kp + (size_t)(j * 64 + r) * E_ + col);
        }
        __syncthreads();

        // S = Q K^T  (A = Q rows, B = K rows as B[k=e][n=key])
        f32x4 sacc[2][4];
        #pragma unroll
        for (int i = 0; i < 2; ++i)
            #pragma unroll
            for (int nt = 0; nt < 4; ++nt) sacc[i][nt] = z;
        #pragma unroll
        for (int kk = 0; kk < 2; ++kk) {
            bf16x8 bfk[4];
            #pragma unroll
            for (int nt = 0; nt < 4; ++nt)
                bfk[nt] = frag(&KVs[nt * 16 + l16][kk * 32 + quad * 8]);
            #pragma unroll
            for (int mt2 = 0; mt2 < 2; ++mt2) {
                bf16x8 af = frag(&Qs[wave * 32 + mt2 * 16 + l16][kk * 32 + quad * 8]);
                #pragma unroll
                for (int nt = 0; nt < 4; ++nt)
                    sacc[mt2][nt] = __builtin_amdgcn_mfma_f32_16x16x32_bf16(
                        af, bfk[nt], sacc[mt2][nt], 0, 0, 0);
            }
        }
        __syncthreads();   // K reads done; KVs free for V

        // issue V loads early (Vt rows e, cols n)
        uint4 vld[2]; int vr[2], vc[2];
        #pragma unroll
        for (int i = 0; i < 2; ++i) {
            int c = tid + i * 256;
            vr[i] = c >> 3; vc[i] = (c & 7) * 8;
            vld[i] = *reinterpret_cast<const uint4*>(
                vp + (size_t)vr[i] * NSEQ + j * 64 + vc[i]);
        }

        // online softmax on C-layout regs: row = quad*4+r (+16*mt2), col key = l16+16*nt
        #pragma unroll
        for (int mt2 = 0; mt2 < 2; ++mt2) {
            #pragma unroll
            for (int nt = 0; nt < 4; ++nt) sacc[mt2][nt] *= inv64;
            #pragma unroll
            for (int r = 0; r < 4; ++r) {
                float sm = fmaxf(fmaxf(sacc[mt2][0][r], sacc[mt2][1][r]),
                                 fmaxf(sacc[mt2][2][r], sacc[mt2][3][r]));
                sm = fmaxf(sm, __shfl_xor(sm, 1));
                sm = fmaxf(sm, __shfl_xor(sm, 2));
                sm = fmaxf(sm, __shfl_xor(sm, 4));
                sm = fmaxf(sm, __shfl_xor(sm, 8));
                float mold = mstate[mt2][r];
                float mnew = fmaxf(mold, sm);
                float al = __expf(mold - mnew);
                mstate[mt2][r] = mnew;
                float ls = 0.f;
                #pragma unroll
                for (int nt = 0; nt < 4; ++nt) {
                    float p = __expf(sacc[mt2][nt][r] - mnew);
                    Ps[wave * 32 + mt2 * 16 + quad * 4 + r][nt * 16 + l16] = f2b(p);
                    ls += p;
                }
                ls += __shfl_xor(ls, 1);
                ls += __shfl_xor(ls, 2);
                ls += __shfl_xor(ls, 4);
                ls += __shfl_xor(ls, 8);
                lstate[mt2][r] = lstate[mt2][r] * al + ls;
                #pragma unroll
                for (int et = 0; et < 4; ++et) oacc[mt2][et][r] *= al;
            }
        }

        #pragma unroll
        for (int i = 0; i < 2; ++i)          // commit V tile to LDS
            *reinterpret_cast<uint4*>(&KVs[vr[i]][vc[i]]) = vld[i];
        __syncthreads();   // P + V visible

        // O += P V  (A = P rows [m][key], B = Vt rows as B[k=key][n=e])
        #pragma unroll
        for (int kk = 0; kk < 2; ++kk) {
            bf16x8 bfv[4];
            #pragma unroll
            for (int et = 0; et < 4; ++et)
                bfv[et] = frag(&KVs[et * 16 + l16][kk * 32 + quad * 8]);
            #pragma unroll
            for (int mt2 = 0; mt2 < 2; ++mt2) {
                bf16x8 af = frag(&Ps[wave * 32 + mt2 * 16 + l16][kk * 32 + quad * 8]);
                #pragma unroll
                for (int et = 0; et < 4; ++et)
                    oacc[mt2][et] = __builtin_amdgcn_mfma_f32_16x16x32_bf16(
                        af, bfv[et], oacc[mt2][et], 0, 0, 0);
            }
        }
        __syncthreads();   // P/V reads done before next staging
    }

    // epilogue: O/l -> bf16 via LDS, coalesced store to head-concat ao[b][n][h*64+e]
    #pragma unroll
    for (int mt2 = 0; mt2 < 2; ++mt2)
        #pragma unroll
        for (int r = 0; r < 4; ++r) {
            float inv = 1.0f / lstate[mt2][r];
            #pragma unroll
            for (int et = 0; et < 4; ++et)
                Ps[wave * 32 + mt2 * 16 + quad * 4 + r][et * 16 + l16] =
                    f2b(oacc[mt2][et][r] * inv);
        }
    __syncthreads();
    unsigned short* aop = AOb + ((size_t)b * NSEQ + n0) * D_ + h * E_;
    #pragma unroll
    for (int i = 0; i < 4; ++i) {
        int c = tid + i * 256;
        int r = c >> 3, col = (c & 7) * 8;
        *reinterpret_cast<uint4*>(aop + (size_t)r * D_ + col) =
            *reinterpret_cast<const uint4*>(&Ps[r][col]);
    }
}

// ---------------------------------------------------------------------------
// Output projection: Out[m][o] = sum_d ao[m][d] * Wout[o][d]. 8192x512x512.
// Block 128(m) x 64(o). fp32 output.
// ---------------------------------------------------------------------------
__global__ __launch_bounds__(256)
void outproj_kernel(const unsigned short* __restrict__ A,
                    const unsigned short* __restrict__ Bt,
                    float* __restrict__ Out) {
    const int m0 = blockIdx.x * 128;
    const int o0 = blockIdx.y * 64;
    const int tid = threadIdx.x;
    const int wave = tid >> 6, lane = tid & 63;
    const int quad = lane >> 4, l16 = lane & 15;

    __shared__ unsigned short As[128][40];
    __shared__ unsigned short Bs[64][40];

    const f32x4 z = {0.f, 0.f, 0.f, 0.f};
    f32x4 acc[2][4];
    #pragma unroll
    for (int i = 0; i < 2; ++i)
        #pragma unroll
        for (int j = 0; j < 4; ++j) acc[i][j] = z;

    const unsigned short* Ap = A + (size_t)m0 * D_;
    const unsigned short* Bp = Bt + (size_t)o0 * D_;

    for (int kt = 0; kt < D_; kt += 32) {
        #pragma unroll
        for (int i = 0; i < 2; ++i) {
            int c = tid + i * 256;
            int r = c >> 2, col = (c & 3) * 8;
            *reinterpret_cast<uint4*>(&As[r][col]) =
                *reinterpret_cast<const uint4*>(Ap + (size_t)r * D_ + kt + col);
        }
        {
            int r = tid >> 2, col = (tid & 3) * 8;
            *reinterpret_cast<uint4*>(&Bs[r][col]) =
                *reinterpret_cast<const uint4*>(Bp + (size_t)r * D_ + kt + col);
        }
        __syncthreads();
        bf16x8 bf[4];
        #pragma unroll
        for (int nt = 0; nt < 4; ++nt) bf[nt] = frag(&Bs[nt * 16 + l16][quad * 8]);
        #pragma unroll
        for (int mt2 = 0; mt2 < 2; ++mt2) {
            bf16x8 af = frag(&As[wave * 32 + mt2 * 16 + l16][quad * 8]);
            #pragma unroll
            for (int nt = 0; nt < 4; ++nt)
                acc[mt2][nt] = __builtin_amdgcn_mfma_f32_16x16x32_bf16(
                    af, bf[nt], acc[mt2][nt], 0, 0, 0);
        }
        __syncthreads();
    }
    #pragma unroll
    for (int mt2 = 0; mt2 < 2; ++mt2)
        #pragma unroll
        for (int nt = 0; nt < 4; ++nt)
            #pragma unroll
            for (int r = 0; r < 4; ++r)
                Out[(size_t)(m0 + wave * 32 + mt2 * 16 + quad * 4 + r) * D_ +
                    o0 + nt * 16 + l16] = acc[mt2][nt][r];
}

// ---------------------------------------------------------------------------
extern "C" void kernel_launch(void* const* d_in, const int* in_sizes, int n_in,
                              void* d_out, int out_size, void* d_ws, size_t ws_size,
                              hipStream_t stream) {
    const float* keys   = (const float*)d_in[0];
    const float* values = (const float*)d_in[1];
    const float* query  = (const float*)d_in[2];
    const float* Wk     = (const float*)d_in[3];
    const float* Wv     = (const float*)d_in[4];
    const float* Wq     = (const float*)d_in[5];
    const float* Wout   = (const float*)d_in[6];
    float* out = (float*)d_out;

    unsigned short* ws16 = (unsigned short*)d_ws;
    const size_t XN = (size_t)B_ * NSEQ * D_;      // 4,194,304
    const size_t WN = (size_t)H_ * D_ * E_;        // 262,144
    unsigned short* xbk = ws16;
    unsigned short* xbv = xbk + XN;
    unsigned short* xbq = xbv + XN;
    unsigned short* wkt = xbq + XN;
    unsigned short* wvt = wkt + WN;
    unsigned short* wqt = wvt + WN;
    unsigned short* wob = wqt + WN;                // Wout bf16 [512][512]
    unsigned short* qb  = wob + WN;                // [B][H][N][E]
    unsigned short* kb  = qb + XN;                 // [B][H][N][E]
    unsigned short* vtb = kb + XN;                 // [B][H][E][N]
    unsigned short* aob = vtb + XN;                // [B][N][D] head-concat
    // total: 7*XN + 4*WN = 30,408,704 ushort = 60.8 MB (round-1 ws was 67 MB)

    cast_x_kernel<<<dim3(4096, 3), 256, 0, stream>>>(keys, values, query, xbk, xbv, xbq);
    cast_w_kernel<<<dim3(1024, 4), 256, 0, stream>>>(Wk, Wv, Wq, Wout, wkt, wvt, wqt, wob);

    dim3 pgrid(NSEQ / 128, H_, B_);   // 512 blocks
    proj_kernel<0><<<pgrid, 256, 0, stream>>>(xbq, wqt, qb);
    proj_kernel<0><<<pgrid, 256, 0, stream>>>(xbk, wkt, kb);
    proj_kernel<1><<<pgrid, 256, 0, stream>>>(xbv, wvt, vtb);

    attn_kernel<<<dim3(NSEQ / 128, H_, B_), 256, 0, stream>>>(qb, kb, vtb, aob);

    outproj_kernel<<<dim3((B_ * NSEQ) / 128, D_ / 64), 256, 0, stream>>>(aob, wob, out);
}